// Round 14
// baseline (317.321 us; speedup 1.0000x reference)
//
#include <hip/hip_runtime.h>
#include <cstdint>
#include <cstddef>

#define HD 128              // hidden channels
#define GD 50               // gaussians
static constexpr float PI_F   = 3.14159265358979323846f;
static constexpr float CUTF   = 6.0f;
static constexpr float SHIFTF = 0.69314718055994530942f; // ln(2)

typedef _Float16 f16x8 __attribute__((ext_vector_type(8)));
typedef _Float16 f16x4 __attribute__((ext_vector_type(4)));
typedef _Float16 f16x2 __attribute__((ext_vector_type(2)));
typedef float    f32x4 __attribute__((ext_vector_type(4)));

struct Ptr8 { const float* p[8]; };

// fast ShiftedSoftplus: native v_exp_f32 / v_log_f32
__device__ __forceinline__ float ssp(float x) {
    float e = __expf(-fabsf(x));
    return fmaxf(x, 0.0f) + __logf(1.0f + e) - SHIFTF;
}

// ---------------------------------------------------------------------------
// Swizzled fp16 LDS tile (16 rows x 128 cols, 256 B/row), XOR G4 fix.
// ---------------------------------------------------------------------------
__device__ __forceinline__ _Float16* t16(_Float16* base, int row, int byte) {
    return (_Float16*)((char*)base + row * 256 + (byte ^ ((row & 7) << 4)));
}

// 8 MFMAs covering 2 column-tiles (ctb, ctb+1) x 4 k-slices
__device__ __forceinline__ void mfma_ct(const f16x8 af[4],
                                        const _Float16* __restrict__ Bf,
                                        int lane, f32x4 acc[2], int ctb) {
    #pragma unroll
    for (int ks = 0; ks < 4; ++ks)
        #pragma unroll
        for (int c = 0; c < 2; ++c)
            acc[c] = __builtin_amdgcn_mfma_f32_16x16x32_f16(
                af[ks], ((const f16x8*)Bf)[((ctb + c) * 4 + ks) * 64 + lane],
                acc[c], 0, 0, 0);
}

// C/D layout (m89): col = lane&15, row_local = (lane>>4)*4 + r
template <int ACT>
__device__ __forceinline__ void acc_to_t16_ct(const f32x4 acc[2], const float* bias,
                                              int lane, _Float16* tile, int ctb) {
    int col0 = lane & 15, r0 = (lane >> 4) * 4;
    #pragma unroll
    for (int c = 0; c < 2; ++c) {
        int cc = (ctb + c) * 16 + col0;
        float bs = bias ? bias[cc] : 0.f;
        #pragma unroll
        for (int r = 0; r < 4; ++r) {
            float o = acc[c][r] + bs;
            if (ACT) o = ssp(o);
            *t16(tile, r0 + r, cc * 2) = (_Float16)o;
        }
    }
}

// A-fragments (lane: row = lane&15, k = (lane>>4)*8 + j per ks) from fp16 tile
__device__ __forceinline__ void t16_to_af(_Float16* tile, int lane, f16x8 af[4]) {
    int row = lane & 15, kgB = (lane >> 4) * 16;
    #pragma unroll
    for (int ks = 0; ks < 4; ++ks)
        af[ks] = *(const f16x8*)t16(tile, row, ks * 64 + kgB);
}

// v(z) for 2 column-tiles in accumulator layout
__device__ __forceinline__ void vz_ct(const float* __restrict__ z,
                                      const float* __restrict__ iw,
                                      const float* __restrict__ ib,
                                      int rowbase, int lane, int n, int ctb,
                                      f32x4 vz[2]) {
    int col0 = lane & 15, r0 = (lane >> 4) * 4;
    float zr[4][3];
    #pragma unroll
    for (int r = 0; r < 4; ++r) {
        int row = min(rowbase + r0 + r, n - 1);
        zr[r][0] = z[row * 3 + 0];
        zr[r][1] = z[row * 3 + 1];
        zr[r][2] = z[row * 3 + 2];
    }
    #pragma unroll
    for (int c = 0; c < 2; ++c) {
        int cc = (ctb + c) * 16 + col0;
        float w0 = iw[cc], w1 = iw[HD + cc], w2 = iw[2 * HD + cc], bz = ib[cc];
        #pragma unroll
        for (int r = 0; r < 4; ++r)
            vz[c][r] = fmaf(zr[r][0], w0, fmaf(zr[r][1], w1, fmaf(zr[r][2], w2, bz)));
    }
}

// ---------------------------------------------------------------------------
// Merged prep kernel, grid (8, 9), 256 threads:
//   y = 0..6 : pack weight slot y into fp16 MFMA B-frag order (2048 frags)
//   y = 7    : zero deg[]
//   y = 8, x<7: Wtab for bin=x, both layers (threads 0-127 = L0, 128-255 = L1)
// ---------------------------------------------------------------------------
__global__ __launch_bounds__(256) void k_wtab_prep(Ptr8 WT, Ptr8 PB,
                                                   float* __restrict__ wtab,
                                                   _Float16* __restrict__ Bf,
                                                   int* __restrict__ deg, int n) {
    int y = blockIdx.y;
    if (y < 7) {
        int idx = blockIdx.x * 256 + threadIdx.x;   // 0..2047
        if (idx >= 2048) return;
        const float* W = PB.p[y];
        int l  = idx & 63;
        int f  = idx >> 6;        // 0..31 = ct*4+ks
        int ks = f & 3, ct = f >> 2;
        int col = ct * 16 + (l & 15);
        int k0  = ks * 32 + ((l >> 4) << 3);
        f16x8 o;
        #pragma unroll
        for (int j = 0; j < 8; ++j) o[j] = (_Float16)W[(size_t)(k0 + j) * HD + col];
        ((f16x8*)(Bf + (size_t)y * 16384))[idx] = o;
        return;
    }
    if (y == 7) {
        int idx = blockIdx.x * 256 + threadIdx.x;
        for (int i = idx; i < n; i += 2048) deg[i] = 0;
        return;
    }
    // y == 8: Wtab
    if (blockIdx.x >= 7) return;
    int bin   = blockIdx.x;
    int layer = threadIdx.x >> 7;     // 0 / 1
    int t     = threadIdx.x & 127;
    const float* m0w = WT.p[layer * 4 + 0];
    const float* m0b = WT.p[layer * 4 + 1];
    const float* m2w = WT.p[layer * 4 + 2];
    const float* m2b = WT.p[layer * 4 + 3];
    __shared__ float hbuf[2][HD];

    const float spacing = CUTF / (GD - 1);
    const float coeff   = -0.5f / (spacing * spacing);

    float acc = m0b[t];
    #pragma unroll 5
    for (int g = 0; g < GD; ++g) {
        float d = (float)bin - (float)g * spacing;
        acc = fmaf(__expf(coeff * d * d), m0w[g * HD + t], acc);
    }
    hbuf[layer][t] = ssp(acc);
    __syncthreads();

    float acc2 = m2b[t];
    #pragma unroll 8
    for (int k = 0; k < HD; ++k)
        acc2 = fmaf(hbuf[layer][k], m2w[k * HD + t], acc2);
    wtab[(layer * 7 + bin) * HD + t] = acc2;
}

// ---------------------------------------------------------------------------
// k_degpos: deg histogram; the atomic's return value IS the local slot ->
// pos[e]. 8 edges/thread, atomics batched before dependent stores.
// ---------------------------------------------------------------------------
__global__ __launch_bounds__(256) void k_degpos(const int* __restrict__ ei,
                                                int* __restrict__ deg,
                                                int* __restrict__ pos,
                                                int nedges) {
    int base = blockIdx.x * 2048 + threadIdx.x;
    int p[8];
    #pragma unroll
    for (int k = 0; k < 8; ++k) {
        int e = base + k * 256;
        if (e < nedges) p[k] = atomicAdd(&deg[ei[nedges + e]], 1);
    }
    #pragma unroll
    for (int k = 0; k < 8; ++k) {
        int e = base + k * 256;
        if (e < nedges) pos[e] = p[k];
    }
}

// ---------------------------------------------------------------------------
// scan1: block-local exclusive scan of deg (n+1 elems) + per-block totals
// ---------------------------------------------------------------------------
__global__ __launch_bounds__(1024) void k_scan1(const int* __restrict__ deg,
                                                int* __restrict__ rowstart,
                                                int* __restrict__ blocksum, int n) {
    __shared__ int wsum[16];
    int tid  = threadIdx.x;
    int lane = tid & 63, wid = tid >> 6;
    int i = blockIdx.x * 1024 + tid;
    int val = (i < n) ? deg[i] : 0;
    int x = val;
    #pragma unroll
    for (int off = 1; off < 64; off <<= 1) {
        int y = __shfl_up(x, off, 64);
        if (lane >= off) x += y;
    }
    if (lane == 63) wsum[wid] = x;
    __syncthreads();
    if (wid == 0) {
        int s = (lane < 16) ? wsum[lane] : 0;
        #pragma unroll
        for (int off = 1; off < 16; off <<= 1) {
            int y = __shfl_up(s, off, 64);
            if (lane >= off) s += y;
        }
        if (lane < 16) wsum[lane] = s;
    }
    __syncthreads();
    int wbase = (wid > 0) ? wsum[wid - 1] : 0;
    if (i <= n) rowstart[i] = wbase + x - val;
    if (tid == 1023) blocksum[blockIdx.x] = wsum[15];
}

// ---------------------------------------------------------------------------
// scan3e: folds the tiny inter-block scan (<=64 blocksums) into each block,
// then adds the global base to rowstart.
// ---------------------------------------------------------------------------
__global__ __launch_bounds__(1024) void k_scan3e(int* __restrict__ rowstart,
                                                 const int* __restrict__ blocksum,
                                                 int nb, int n) {
    __shared__ int sbase[64];
    int tid = threadIdx.x;
    if (tid < 64) {
        int v = (tid < nb) ? blocksum[tid] : 0;
        int x = v;
        #pragma unroll
        for (int off = 1; off < 64; off <<= 1) {
            int y = __shfl_up(x, off, 64);
            if (tid >= off) x += y;
        }
        sbase[tid] = x;                    // inclusive scan
    }
    __syncthreads();
    int bx = blockIdx.x;
    int base = (bx > 0) ? sbase[bx - 1] : 0;
    int i = bx * 1024 + tid;
    if (i <= n) rowstart[i] += base;
}

// ---------------------------------------------------------------------------
// Fused: ewrite (blocks [0,e8Grid)) + front (blocks after).
// ---------------------------------------------------------------------------
__global__ __launch_bounds__(256) void k_ewf(const int* __restrict__ ei,
                                             const float* __restrict__ dist,
                                             const int* __restrict__ pos,
                                             const int* __restrict__ rowstart,
                                             int2* __restrict__ ecomb,
                                             int nedges, int e8Grid,
                                             const float* __restrict__ z,
                                             const float* __restrict__ iw,
                                             const float* __restrict__ ib,
                                             const _Float16* __restrict__ BfL,
                                             _Float16* __restrict__ vlin_h, int n) {
    __shared__ __attribute__((aligned(16))) _Float16 tile16[2048];
    int bx = blockIdx.x;
    if (bx < e8Grid) {
        int base = bx * 2048 + (int)threadIdx.x;
        #pragma unroll
        for (int k = 0; k < 8; ++k) {
            int e = base + k * 256;
            if (e < nedges) {
                int   i = ei[nedges + e];
                int   j = ei[e];
                float d = dist[e];
                int bin = min((int)d, 6);
                float Cg = 0.5f * (cosf(d * (PI_F / CUTF)) + 1.0f);
                unsigned long long payload =
                    (unsigned long long)(unsigned)(j | (bin << 25)) |
                    ((unsigned long long)(unsigned)__float_as_int(Cg) << 32);
                __builtin_nontemporal_store(
                    payload, (unsigned long long*)&ecomb[rowstart[i] + pos[e]]);
            }
        }
        return;
    }
    // ---- front ----
    int tid = threadIdx.x, lane = tid & 63, wid = tid >> 6;
    int rowbase = (bx - e8Grid) * 16;
    int arow = min(rowbase + (lane & 15), n - 1);
    float z0 = z[arow * 3 + 0], z1 = z[arow * 3 + 1], z2 = z[arow * 3 + 2];
    int kg = (lane >> 4) * 8;

    f16x8 af[4];
    #pragma unroll
    for (int ks = 0; ks < 4; ++ks) {
        f16x8 h;
        #pragma unroll
        for (int j = 0; j < 8; ++j) {
            int c = ks * 32 + kg + j;
            h[j] = (_Float16)fmaf(z0, iw[c], fmaf(z1, iw[HD + c], fmaf(z2, iw[2 * HD + c], ib[c])));
        }
        af[ks] = h;
    }

    f32x4 acc[2];
    acc[0] = (f32x4){0.f, 0.f, 0.f, 0.f};
    acc[1] = (f32x4){0.f, 0.f, 0.f, 0.f};
    mfma_ct(af, BfL, lane, acc, wid * 2);
    acc_to_t16_ct<0>(acc, nullptr, lane, tile16, wid * 2);
    __syncthreads();
    int row = tid >> 4, g8 = tid & 15;
    if (rowbase + row < n)
        ((f16x8*)vlin_h)[(size_t)(rowbase + row) * 16 + g8] =
            *(const f16x8*)t16(tile16, row, g8 * 16);
}

// ---------------------------------------------------------------------------
// agg_h[node] = fp16( sum_e vlin_h[j_e] * Wtab[bin_e] * Cg_e )  (fp32 acc)
// One wave per node. NEW: 2 edges in parallel per wave — lanes 0-31 even
// edges, lanes 32-63 odd edges, 4 channels/lane (f16x4). Halves the serial
// iteration count at identical traffic; shfl_xor(32) combines halves.
// ---------------------------------------------------------------------------
__global__ __launch_bounds__(256) void k_agg(const int* __restrict__ rowstart,
                                             const int2* __restrict__ ecomb,
                                             const _Float16* __restrict__ vlin_h,
                                             const float* __restrict__ wtab,
                                             _Float16* __restrict__ agg_h, int n) {
    __shared__ float lwt[7 * HD];
    int tid = threadIdx.x;
    if (tid < 224) ((float4*)lwt)[tid] = ((const float4*)wtab)[tid];
    __syncthreads();

    int node = blockIdx.x * 4 + (tid >> 6);
    if (node >= n) return;
    int lane = tid & 63;
    int half = lane >> 5;          // 0: even edges, 1: odd edges
    int cl   = lane & 31;          // channels 4*cl .. 4*cl+3
    int beg = rowstart[node], end = rowstart[node + 1];

    float a0 = 0.f, a1 = 0.f, a2 = 0.f, a3 = 0.f;
    const float* lwt4 = lwt + 4 * cl;

    int base = beg;
    for (; base + 7 < end; base += 8) {       // 4 pair-steps = 8 edges
        int2 cc[4];
        #pragma unroll
        for (int k = 0; k < 4; ++k) cc[k] = ecomb[base + 2 * k + half];
        f16x4 hh[4];
        #pragma unroll
        for (int k = 0; k < 4; ++k)
            hh[k] = *(const f16x4*)(vlin_h + (size_t)(cc[k].x & 0x01FFFFFF) * HD + 4 * cl);
        float4 ww[4];
        #pragma unroll
        for (int k = 0; k < 4; ++k)
            ww[k] = *(const float4*)(lwt4 + (cc[k].x >> 25) * HD);
        #pragma unroll
        for (int k = 0; k < 4; ++k) {
            float g = __int_as_float(cc[k].y);
            a0 = fmaf((float)hh[k][0], ww[k].x * g, a0);
            a1 = fmaf((float)hh[k][1], ww[k].y * g, a1);
            a2 = fmaf((float)hh[k][2], ww[k].z * g, a2);
            a3 = fmaf((float)hh[k][3], ww[k].w * g, a3);
        }
    }
    for (; base < end; base += 2) {           // tail, pairwise
        int e = base + half;
        if (e < end) {
            int2 c0 = ecomb[e];
            f16x4 h = *(const f16x4*)(vlin_h + (size_t)(c0.x & 0x01FFFFFF) * HD + 4 * cl);
            float4 w = *(const float4*)(lwt4 + (c0.x >> 25) * HD);
            float g = __int_as_float(c0.y);
            a0 = fmaf((float)h[0], w.x * g, a0);
            a1 = fmaf((float)h[1], w.y * g, a1);
            a2 = fmaf((float)h[2], w.z * g, a2);
            a3 = fmaf((float)h[3], w.w * g, a3);
        }
    }
    // combine even/odd halves
    a0 += __shfl_xor(a0, 32, 64);
    a1 += __shfl_xor(a1, 32, 64);
    a2 += __shfl_xor(a2, 32, 64);
    a3 += __shfl_xor(a3, 32, 64);
    if (half == 0) {
        f16x4 o;
        o[0] = (_Float16)a0; o[1] = (_Float16)a1;
        o[2] = (_Float16)a2; o[3] = (_Float16)a3;
        *(f16x4*)(agg_h + (size_t)node * HD + 4 * cl) = o;
    }
}

// ---------------------------------------------------------------------------
// k_mid: 16 rows/block, 4 waves x 2 ct. tmp=ssp(agg@l1+b1);
// vnew = v(z) + tmp@l2 + b2 -> vres (acc layout); vlin_h = f16(vnew@lin1)
// ---------------------------------------------------------------------------
__global__ __launch_bounds__(256) void k_mid(const _Float16* __restrict__ agg_h,
                                             const _Float16* __restrict__ Bf1,
                                             const float* __restrict__ b1,
                                             const _Float16* __restrict__ Bf2,
                                             const float* __restrict__ b2,
                                             const _Float16* __restrict__ BfL,
                                             const float* __restrict__ z,
                                             const float* __restrict__ iw,
                                             const float* __restrict__ ib,
                                             f32x4* __restrict__ vres4,
                                             _Float16* __restrict__ vlin_h, int n) {
    __shared__ __attribute__((aligned(16))) _Float16 tile16[2048];
    int tid = threadIdx.x, lane = tid & 63, wid = tid >> 6;
    int rowbase = blockIdx.x * 16;
    int ctb = wid * 2;

    int arow = min(rowbase + (lane & 15), n - 1);
    int kg = (lane >> 4) * 8;
    f16x8 af[4];
    #pragma unroll
    for (int ks = 0; ks < 4; ++ks)
        af[ks] = *(const f16x8*)(agg_h + (size_t)arow * HD + ks * 32 + kg);

    f32x4 acc[2];
    acc[0] = (f32x4){0.f, 0.f, 0.f, 0.f};
    acc[1] = (f32x4){0.f, 0.f, 0.f, 0.f};
    mfma_ct(af, Bf1, lane, acc, ctb);
    acc_to_t16_ct<1>(acc, b1, lane, tile16, ctb);     // tmp cols
    __syncthreads();                                  // tmp complete
    t16_to_af(tile16, lane, af);
    __syncthreads();                                  // all reads done

    acc[0] = (f32x4){0.f, 0.f, 0.f, 0.f};
    acc[1] = (f32x4){0.f, 0.f, 0.f, 0.f};
    mfma_ct(af, Bf2, lane, acc, ctb);

    f32x4 vz[2];
    vz_ct(z, iw, ib, rowbase, lane, n, ctb, vz);
    int col0 = lane & 15;
    #pragma unroll
    for (int c = 0; c < 2; ++c) {
        float bs = b2[(ctb + c) * 16 + col0];
        #pragma unroll
        for (int r = 0; r < 4; ++r) acc[c][r] += bs + vz[c][r];
        vres4[((size_t)blockIdx.x * 8 + ctb + c) * 64 + lane] = acc[c];
    }

    acc_to_t16_ct<0>(acc, nullptr, lane, tile16, ctb);  // vnew cols
    __syncthreads();                                    // vnew complete
    t16_to_af(tile16, lane, af);
    __syncthreads();                                    // reads done

    acc[0] = (f32x4){0.f, 0.f, 0.f, 0.f};
    acc[1] = (f32x4){0.f, 0.f, 0.f, 0.f};
    mfma_ct(af, BfL, lane, acc, ctb);
    acc_to_t16_ct<0>(acc, nullptr, lane, tile16, ctb);
    __syncthreads();                                    // vlin tile complete
    int row = tid >> 4, g8 = tid & 15;
    if (rowbase + row < n)
        ((f16x8*)vlin_h)[(size_t)(rowbase + row) * 16 + g8] =
            *(const f16x8*)t16(tile16, row, g8 * 16);
}

// ---------------------------------------------------------------------------
// k_back: 16 rows/block. tmp=ssp(agg@l1+b1); vnew = vres + tmp@l2 + b2;
// u = ssp(vnew@u1+ub1); out = u @ u_l2[128,3] + ub2 (shfl + LDS reduce)
// ---------------------------------------------------------------------------
__global__ __launch_bounds__(256) void k_back(const _Float16* __restrict__ agg_h,
                                              const _Float16* __restrict__ Bf1,
                                              const float* __restrict__ b1,
                                              const _Float16* __restrict__ Bf2,
                                              const float* __restrict__ b2,
                                              const _Float16* __restrict__ BfU,
                                              const float* __restrict__ ub1,
                                              const float* __restrict__ w2,
                                              const float* __restrict__ ub2,
                                              const f32x4* __restrict__ vres4,
                                              float* __restrict__ out, int n) {
    __shared__ __attribute__((aligned(16))) _Float16 tile16[2048];
    __shared__ float red[4][16][3];
    int tid = threadIdx.x, lane = tid & 63, wid = tid >> 6;
    int rowbase = blockIdx.x * 16;
    int ctb = wid * 2;

    int arow = min(rowbase + (lane & 15), n - 1);
    int kg = (lane >> 4) * 8;
    f16x8 af[4];
    #pragma unroll
    for (int ks = 0; ks < 4; ++ks)
        af[ks] = *(const f16x8*)(agg_h + (size_t)arow * HD + ks * 32 + kg);

    f32x4 acc[2];
    acc[0] = (f32x4){0.f, 0.f, 0.f, 0.f};
    acc[1] = (f32x4){0.f, 0.f, 0.f, 0.f};
    mfma_ct(af, Bf1, lane, acc, ctb);
    acc_to_t16_ct<1>(acc, b1, lane, tile16, ctb);
    __syncthreads();
    t16_to_af(tile16, lane, af);
    __syncthreads();

    acc[0] = (f32x4){0.f, 0.f, 0.f, 0.f};
    acc[1] = (f32x4){0.f, 0.f, 0.f, 0.f};
    mfma_ct(af, Bf2, lane, acc, ctb);

    int col0 = lane & 15;
    #pragma unroll
    for (int c = 0; c < 2; ++c) {
        float bs = b2[(ctb + c) * 16 + col0];
        f32x4 rv = vres4[((size_t)blockIdx.x * 8 + ctb + c) * 64 + lane];
        #pragma unroll
        for (int r = 0; r < 4; ++r) acc[c][r] += bs + rv[r];
    }

    acc_to_t16_ct<0>(acc, nullptr, lane, tile16, ctb);
    __syncthreads();
    t16_to_af(tile16, lane, af);
    // tile is not written again — no further barrier needed before MFMA

    acc[0] = (f32x4){0.f, 0.f, 0.f, 0.f};
    acc[1] = (f32x4){0.f, 0.f, 0.f, 0.f};
    mfma_ct(af, BfU, lane, acc, ctb);

    // readout partials over this wave's 32 cols
    int r0 = (lane >> 4) * 4;
    float p0[4] = {0.f, 0.f, 0.f, 0.f};
    float p1[4] = {0.f, 0.f, 0.f, 0.f};
    float p2[4] = {0.f, 0.f, 0.f, 0.f};
    #pragma unroll
    for (int c = 0; c < 2; ++c) {
        int cc = (ctb + c) * 16 + col0;
        float bu = ub1[cc];
        float w20 = w2[cc * 3 + 0], w21 = w2[cc * 3 + 1], w22 = w2[cc * 3 + 2];
        #pragma unroll
        for (int r = 0; r < 4; ++r) {
            float u = ssp(acc[c][r] + bu);
            p0[r] = fmaf(u, w20, p0[r]);
            p1[r] = fmaf(u, w21, p1[r]);
            p2[r] = fmaf(u, w22, p2[r]);
        }
    }
    #pragma unroll
    for (int m = 1; m < 16; m <<= 1) {
        #pragma unroll
        for (int r = 0; r < 4; ++r) {
            p0[r] += __shfl_xor(p0[r], m, 64);
            p1[r] += __shfl_xor(p1[r], m, 64);
            p2[r] += __shfl_xor(p2[r], m, 64);
        }
    }
    if (col0 == 0) {
        #pragma unroll
        for (int r = 0; r < 4; ++r) {
            red[wid][r0 + r][0] = p0[r];
            red[wid][r0 + r][1] = p1[r];
            red[wid][r0 + r][2] = p2[r];
        }
    }
    __syncthreads();
    if (tid < 48) {
        int row = tid / 3, c = tid % 3;
        float s = red[0][row][c] + red[1][row][c] + red[2][row][c] + red[3][row][c];
        if (rowbase + row < n)
            out[(size_t)(rowbase + row) * 3 + c] = s + ub2[c];
    }
}

// ---------------------------------------------------------------------------
extern "C" void kernel_launch(void* const* d_in, const int* in_sizes, int n_in,
                              void* d_out, int out_size, void* d_ws, size_t ws_size,
                              hipStream_t stream) {
    const float* z      = (const float*)d_in[0];
    const float* dist   = (const float*)d_in[1];
    const int*   ei     = (const int*)d_in[2];
    const float* init_w = (const float*)d_in[3];
    const float* init_b = (const float*)d_in[4];

    const float* L[2][9];
    for (int l = 0; l < 2; ++l)
        for (int p = 0; p < 9; ++p)
            L[l][p] = (const float*)d_in[5 + l * 9 + p];

    const float* u_l1_w = (const float*)d_in[23];
    const float* u_l1_b = (const float*)d_in[24];
    const float* u_l2_w = (const float*)d_in[25];
    const float* u_l2_b = (const float*)d_in[26];
    float* out = (float*)d_out;

    const int N = in_sizes[0] / 3;
    const int E = in_sizes[1];

    const int nb16     = (N + 15) / 16;           // 16-row blocks
    const int e8Grid   = (E + 2047) / 2048;       // 8 edges/thread
    const int scanB    = (N + 1 + 1023) / 1024;
    const int aggGrid  = (N + 3) / 4;

    // workspace layout (float units)
    float* wtab   = (float*)d_ws;                     // 2048
    float* bf     = wtab + 2048;                      // 57344
    float* vres   = bf + 57344;                       // nb16*2048 (acc layout)
    float* vh     = vres + (size_t)nb16 * 2048;       // N*64
    float* aggh   = vh + (size_t)N * 64;              // N*64
    int2*  ecomb  = (int2*)(aggh + (size_t)N * 64);   // E int2
    int*   pos    = (int*)(ecomb + E);                // E
    int*   deg    = pos + E;                          // N
    int*   rowstart = deg + N;                        // N+1
    int*   blocksum = rowstart + N + 1;               // 64

    _Float16* vlin_h = (_Float16*)vh;
    _Float16* agg_h  = (_Float16*)aggh;
    f32x4*    vres4  = (f32x4*)vres;
    _Float16* Bf     = (_Float16*)bf;
    _Float16* BfW[7];
    for (int i = 0; i < 7; ++i) BfW[i] = Bf + (size_t)i * 16384;

    Ptr8 wt; wt.p[0] = L[0][1]; wt.p[1] = L[0][2]; wt.p[2] = L[0][3]; wt.p[3] = L[0][4];
             wt.p[4] = L[1][1]; wt.p[5] = L[1][2]; wt.p[6] = L[1][3]; wt.p[7] = L[1][4];
    Ptr8 pb; pb.p[0] = L[0][0]; pb.p[1] = L[0][5]; pb.p[2] = L[0][7];
             pb.p[3] = L[1][0]; pb.p[4] = L[1][5]; pb.p[5] = L[1][7];
             pb.p[6] = u_l1_w;  pb.p[7] = u_l1_w;

    // prep: pack 7 weights + zero deg + both layers' Wtab, one launch
    k_wtab_prep<<<dim3(8, 9), 256, 0, stream>>>(wt, pb, wtab, Bf, deg, N);

    // CSR build: ONE atomic pass (deg + local slot), scan
    k_degpos<<<e8Grid, 256, 0, stream>>>(ei, deg, pos, E);
    k_scan1<<<scanB, 1024, 0, stream>>>(deg, rowstart, blocksum, N);
    k_scan3e<<<scanB, 1024, 0, stream>>>(rowstart, blocksum, scanB, N);

    // placement write (NT stores) fused with layer-0 front
    k_ewf<<<e8Grid + nb16, 256, 0, stream>>>(ei, dist, pos, rowstart, ecomb, E, e8Grid,
                                             z, init_w, init_b, BfW[0], vlin_h, N);

    k_agg<<<aggGrid, 256, 0, stream>>>(rowstart, ecomb, vlin_h, wtab, agg_h, N);
    k_mid<<<nb16, 256, 0, stream>>>(agg_h, BfW[1], L[0][6], BfW[2], L[0][8],
                                    BfW[3], z, init_w, init_b, vres4, vlin_h, N);
    k_agg<<<aggGrid, 256, 0, stream>>>(rowstart, ecomb, vlin_h, wtab + 7 * HD, agg_h, N);
    k_back<<<nb16, 256, 0, stream>>>(agg_h, BfW[4], L[1][6], BfW[5], L[1][8],
                                     BfW[6], u_l1_b, u_l2_w, u_l2_b, vres4, out, N);
}